// Round 12
// baseline (298.358 us; speedup 1.0000x reference)
//
#include <hip/hip_runtime.h>
#include <hip/hip_bf16.h>
#include <cstdint>

typedef float f32x4 __attribute__((ext_vector_type(4)));
typedef __bf16 bf16x8 __attribute__((ext_vector_type(8)));

#define BS 128
#define NSP 196
#define NTM 32
#define DDIM 768

__device__ inline ushort4 f4_to_bf4(float4 v)
{
    ushort4 u;
    u.x = __builtin_bit_cast(unsigned short, (__bf16)v.x);
    u.y = __builtin_bit_cast(unsigned short, (__bf16)v.y);
    u.z = __builtin_bit_cast(unsigned short, (__bf16)v.z);
    u.w = __builtin_bit_cast(unsigned short, (__bf16)v.w);
    return u;
}

__device__ inline float sumsq4(float4 a)
{
    return fmaf(a.x, a.x, fmaf(a.y, a.y, fmaf(a.z, a.z, a.w * a.w)));
}

// sum over the 16-lane DPP row; every lane gets the total.
__device__ inline float row16_sum(float x)
{
    int t;
    t = __builtin_amdgcn_update_dpp(0, __builtin_bit_cast(int, x), 0x121, 0xf, 0xf, true);
    x += __builtin_bit_cast(float, t);
    t = __builtin_amdgcn_update_dpp(0, __builtin_bit_cast(int, x), 0x122, 0xf, 0xf, true);
    x += __builtin_bit_cast(float, t);
    t = __builtin_amdgcn_update_dpp(0, __builtin_bit_cast(int, x), 0x124, 0xf, 0xf, true);
    x += __builtin_bit_cast(float, t);
    t = __builtin_amdgcn_update_dpp(0, __builtin_bit_cast(int, x), 0x128, 0xf, 0xf, true);
    x += __builtin_bit_cast(float, t);
    return x;
}

// ---------------- temporal row inverse-norms only ----------------
__global__ __launch_bounds__(256)
void tm_norm_kernel(const float* __restrict__ tm1, const float* __restrict__ tm2,
                    float* __restrict__ inx_tm, float* __restrict__ iny_tm)
{
    int B = blockIdx.x;
    const float* src; float* inv;
    if (B < 1024) { src = tm1; inv = inx_tm; }
    else          { B -= 1024; src = tm2; inv = iny_tm; }
    const int row  = B * 4 + (threadIdx.x >> 6);
    const int lane = threadIdx.x & 63;
    const float4* p = reinterpret_cast<const float4*>(src + (size_t)row * DDIM);
    float ss = 0.f;
#pragma unroll
    for (int c = 0; c < 3; ++c) ss += sumsq4(p[lane + 64 * c]);
#pragma unroll
    for (int off = 32; off; off >>= 1) ss += __shfl_xor(ss, off, 64);
    if (lane == 0) inv[row] = 1.0f / (sqrtf(ss) + 1e-12f);
}

// ====== spatial cost GEMM v2: 128x64 tile, 3 blocks/CU, deep prefetch =======
// Grid 1024 = 8 XCD * 16 batch * 2 rowtile * 4 coltile. Block 256 thr (4 waves).
// BK=64, dbuf LDS (48KB) + XOR slot swizzle, ONE barrier/K-tile.
// A-regs double-buffered (2-tile prefetch), B-regs single (1-tile), B issued
// first so the vmcnt wait at WRITES leaves next-next A in flight.
// Row sumsq fused during staging; A = exp(2*cos-2) bf16 -> A_sp[b][.][256].
#define V2_LDSE 12288      // bf16 elems per buffer: A 128*64 + B 64*64
__global__ __launch_bounds__(256, 3)
void cost_gemm_v2(const float* __restrict__ X, const float* __restrict__ Y,
                  __bf16* __restrict__ Aout)
{
    __shared__ __bf16 lds[2 * V2_LDSE];    // 49,152 B
    float* ldsF = reinterpret_cast<float*>(lds);

    const int flat = blockIdx.x;
    const int xcd  = flat & 7;
    const int s    = flat >> 3;            // 0..127
    const int b    = xcd * 16 + (s >> 3);
    const int rt_  = (s >> 2) & 1;
    const int ct_  = s & 3;
    const int r0   = rt_ * 128;
    const int n0   = (ct_ < 3) ? ct_ * 64 : 132;

    const int tid = threadIdx.x;
    const int w = tid >> 6, lane = tid & 63;
    const int q = lane >> 4, l16 = lane & 15;
    const int rA  = tid >> 4;              // 0..15
    const int kq  = tid & 15;              // 0..15
    const int slt = kq >> 1;               // 16B slot
    const int hof = (kq & 1) * 4;          // half-slot elem offset

    const float* Yb = Y + ((size_t)b * NSP + n0) * DDIM;

    int arow[8];
#pragma unroll
    for (int j = 0; j < 8; ++j) {
        int ri = r0 + rA + 16 * j;
        arow[j] = b * NSP + min(ri, NSP - 1);    // clamp: no OOB, masked at store
    }

    float4 aR[2][8], bR[4];
    float ssA[8] = {0.f, 0.f, 0.f, 0.f, 0.f, 0.f, 0.f, 0.f};
    float ssB[4] = {0.f, 0.f, 0.f, 0.f};

    auto LOADSA = [&](int d, int k0) {
#pragma unroll
        for (int j = 0; j < 8; ++j)
            aR[d][j] = *reinterpret_cast<const float4*>(X + (size_t)arow[j] * DDIM + k0 + kq * 4);
    };
    auto LOADSB = [&](int k0) {
#pragma unroll
        for (int j = 0; j < 4; ++j)
            bR[j] = *reinterpret_cast<const float4*>(Yb + (size_t)(rA + 16 * j) * DDIM + k0 + kq * 4);
    };
    auto WRITES = [&](int d, int buf) {
#pragma unroll
        for (int j = 0; j < 8; ++j) {
            int r = rA + 16 * j;
            ssA[j] += sumsq4(aR[d][j]);
            *reinterpret_cast<ushort4*>(&lds[buf * V2_LDSE + r * 64 + ((slt ^ (r & 7)) << 3) + hof]) =
                f4_to_bf4(aR[d][j]);
        }
#pragma unroll
        for (int j = 0; j < 4; ++j) {
            int r = rA + 16 * j;
            ssB[j] += sumsq4(bR[j]);
            *reinterpret_cast<ushort4*>(&lds[buf * V2_LDSE + 8192 + r * 64 + ((slt ^ (r & 7)) << 3) + hof]) =
                f4_to_bf4(bR[j]);
        }
    };

    f32x4 acc[2][4];
#pragma unroll
    for (int i = 0; i < 2; ++i)
#pragma unroll
        for (int j = 0; j < 4; ++j) acc[i][j] = f32x4{0.f, 0.f, 0.f, 0.f};

    LOADSB(0);
    LOADSA(0, 0);
    LOADSA(1, 64);
    int buf = 0;
    for (int kt = 0; kt < 12; ++kt) {
        WRITES(kt & 1, buf);
        if (kt < 11) LOADSB((kt + 1) * 64);          // B first: vmcnt leaves A(kt+2) in flight
        if (kt < 10) LOADSA(kt & 1, (kt + 2) * 64);
        __syncthreads();
#pragma unroll
        for (int ks = 0; ks < 2; ++ks) {
            bf16x8 af[2], bfr[4];
#pragma unroll
            for (int rt = 0; rt < 2; ++rt) {
                int r = w * 32 + rt * 16 + l16;
                af[rt] = *reinterpret_cast<const bf16x8*>(
                    &lds[buf * V2_LDSE + r * 64 + (((ks * 4 + q) ^ (r & 7)) << 3)]);
            }
#pragma unroll
            for (int ct = 0; ct < 4; ++ct) {
                int r = ct * 16 + l16;
                bfr[ct] = *reinterpret_cast<const bf16x8*>(
                    &lds[buf * V2_LDSE + 8192 + r * 64 + (((ks * 4 + q) ^ (r & 7)) << 3)]);
            }
#pragma unroll
            for (int ct = 0; ct < 4; ++ct)
#pragma unroll
                for (int rt = 0; rt < 2; ++rt)
                    acc[rt][ct] = __builtin_amdgcn_mfma_f32_16x16x32_bf16(af[rt], bfr[ct], acc[rt][ct], 0, 0, 0);
        }
        buf ^= 1;
    }
    __syncthreads();

    // ---- norm-partial reduce through freed LDS: A rows [r*16+kq], B at +2048 ----
#pragma unroll
    for (int j = 0; j < 8; ++j) ldsF[(rA + 16 * j) * 16 + kq] = ssA[j];
#pragma unroll
    for (int j = 0; j < 4; ++j) ldsF[2048 + (rA + 16 * j) * 16 + kq] = ssB[j];
    __syncthreads();

    float ivy[4];
#pragma unroll
    for (int ct = 0; ct < 4; ++ct) {
        int jr = ct * 16 + l16;
        const f32x4* p = reinterpret_cast<const f32x4*>(&ldsF[2048 + jr * 16]);
        f32x4 t = p[0] + p[1] + p[2] + p[3];
        ivy[ct] = 1.0f / (sqrtf((t.x + t.y) + (t.z + t.w)) + 1e-12f);
    }
#pragma unroll
    for (int rt = 0; rt < 2; ++rt)
#pragma unroll
        for (int rr = 0; rr < 4; ++rr) {
            int i = w * 32 + rt * 16 + q * 4 + rr;
            int gi = r0 + i;
            if (gi < NSP) {
                const f32x4* p = reinterpret_cast<const f32x4*>(&ldsF[i * 16]);
                f32x4 t = p[0] + p[1] + p[2] + p[3];
                float ivx = 1.0f / (sqrtf((t.x + t.y) + (t.z + t.w)) + 1e-12f);
#pragma unroll
                for (int ct = 0; ct < 4; ++ct) {
                    float cs = acc[rt][ct][rr] * ivx * ivy[ct];
                    Aout[(size_t)b * 65536 + (size_t)gi * 256 + (n0 + ct * 16 + l16)] =
                        (__bf16)__expf(2.0f * cs - 2.0f);
                }
            }
        }
}

// ---------------- temporal cost GEMM (f32 in/out) ----------------
template<int WROWS, int NWAVES, int BN, int NPTS>
__global__ __launch_bounds__(NWAVES * 64)
void cost_gemm(const float* __restrict__ X, const float* __restrict__ Y,
               const float* __restrict__ invx, const float* __restrict__ invy,
               float* __restrict__ Aout)
{
    constexpr int MT = WROWS * NWAVES;
    constexpr int CT = BN / 16;
    constexpr int RT = WROWS / 16;
    constexpr int KP = 40;
    constexpr int NTH = NWAVES * 64;
    __shared__ __bf16 As[MT][KP];
    __shared__ __bf16 Bs[BN][KP];

    const int b    = blockIdx.y;
    const int row0 = blockIdx.x * MT;
    const int tid  = threadIdx.x;
    const int w    = tid >> 6, lane = tid & 63;
    const int q    = lane >> 4, l16 = lane & 15;
    const float* Xb = X + (size_t)b * NPTS * DDIM;
    const float* Yb = Y + (size_t)b * NPTS * DDIM;

    f32x4 acc[RT][CT];
#pragma unroll
    for (int i = 0; i < RT; ++i)
#pragma unroll
        for (int j = 0; j < CT; ++j) acc[i][j] = f32x4{0.f, 0.f, 0.f, 0.f};

    for (int k0 = 0; k0 < DDIM; k0 += 32) {
        __syncthreads();
        for (int idx = tid * 4; idx < MT * 32; idx += NTH * 4) {
            int r = idx >> 5, kk = idx & 31;
            int gr = row0 + r;
            float4 v = {0.f, 0.f, 0.f, 0.f};
            if (gr < NPTS) v = *reinterpret_cast<const float4*>(Xb + (size_t)gr * DDIM + k0 + kk);
            *reinterpret_cast<ushort4*>(&As[r][kk]) = f4_to_bf4(v);
        }
        for (int idx = tid * 4; idx < BN * 32; idx += NTH * 4) {
            int r = idx >> 5, kk = idx & 31;
            float4 v = {0.f, 0.f, 0.f, 0.f};
            if (r < NPTS) v = *reinterpret_cast<const float4*>(Yb + (size_t)r * DDIM + k0 + kk);
            *reinterpret_cast<ushort4*>(&Bs[r][kk]) = f4_to_bf4(v);
        }
        __syncthreads();

        bf16x8 af[RT];
#pragma unroll
        for (int rt = 0; rt < RT; ++rt)
            af[rt] = *reinterpret_cast<const bf16x8*>(&As[w * WROWS + rt * 16 + l16][q * 8]);
#pragma unroll
        for (int ct = 0; ct < CT; ++ct) {
            bf16x8 bfr = *reinterpret_cast<const bf16x8*>(&Bs[ct * 16 + l16][q * 8]);
#pragma unroll
            for (int rt = 0; rt < RT; ++rt)
                acc[rt][ct] = __builtin_amdgcn_mfma_f32_16x16x32_bf16(af[rt], bfr, acc[rt][ct], 0, 0, 0);
        }
    }

#pragma unroll
    for (int rt = 0; rt < RT; ++rt)
#pragma unroll
        for (int ct = 0; ct < CT; ++ct)
#pragma unroll
            for (int rr = 0; rr < 4; ++rr) {
                int i = row0 + w * WROWS + rt * 16 + q * 4 + rr;
                int j = ct * 16 + l16;
                if (i < NPTS && j < NPTS) {
                    float g  = acc[rt][ct][rr];
                    float cs = g * invx[b * NPTS + i] * invy[b * NPTS + j];
                    Aout[(size_t)b * NPTS * NPTS + (size_t)i * NPTS + j] = expf(-2.0f * (1.0f - cs));
                }
            }
}

// ========== fused IPOT v6: DPP rowsum, 512 thr, A in LDS ==========
__global__ __launch_bounds__(512, 1)
void ipot_dpp(const __bf16* __restrict__ Asp, const float* __restrict__ Atm,
              float* __restrict__ out)
{
    __shared__ __bf16 Alds[224 * 256];    // 114,688 B
    __shared__ float  cpart[32 * 260];    //  33,280 B
    __shared__ float  svec[2][272];
    __shared__ float  wsum[8];

    const int B = blockIdx.x;
    if (B >= 128) {
        if (threadIdx.x >= 64) return;
        const int b = B - 128;
        const float* Ab = Atm + (size_t)b * NTM * NTM;
        const int lane = threadIdx.x;
        const int rh = lane >> 5, cj = lane & 31;
        constexpr float MIU = 1.f / NTM;
        float A[16], P[16];
#pragma unroll
        for (int k = 0; k < 16; ++k) {
            A[k] = Ab[(rh + 2 * k) * NTM + cj];
            P[k] = 1.f;
        }
        float sv = MIU;
        for (int it = 0; it < 20; ++it) {
#pragma unroll
            for (int k = 0; k < 16; ++k) {
                P[k] *= A[k];
                float acc = row16_sum(P[k] * sv);
                acc += __shfl_xor(acc, 16);
                P[k] *= MIU * __builtin_amdgcn_rcpf(acc + 1e-6f);
            }
            float cssum = 0.f;
#pragma unroll
            for (int k = 0; k < 16; ++k) cssum += P[k];
            cssum += __shfl_xor(cssum, 32);
            float sg = MIU * __builtin_amdgcn_rcpf(cssum + 1e-6f);
#pragma unroll
            for (int k = 0; k < 16; ++k) P[k] *= sg;
            sv = sg;
        }
        float acc = 0.f;
#pragma unroll
        for (int k = 0; k < 16; ++k)
            acc = fmaf(P[k], -0.5f * __logf(A[k]), acc);
        acc = row16_sum(acc);
        acc += __shfl_xor(acc, 16);
        acc += __shfl_xor(acc, 32);
        if (lane == 0) atomicAdd(out, -acc * (1.f / BS));
        return;
    }

    const int b = (B & 7) * 16 + (B >> 3);
    const __bf16* Ab = Asp + (size_t)b * 65536;
    const int tid = threadIdx.x;
    const int w = tid >> 6, lane = tid & 63;
    const int rq = lane >> 4, cl = lane & 15;
    const int g = w * 4 + rq;
    const int colbase = cl * 8;
    constexpr float MIU = 1.f / NSP;

    for (int idx = tid; idx < NSP * 32; idx += 512) {
        int r = idx >> 5, c = idx & 31;
        bf16x8 v;
#pragma unroll
        for (int i = 0; i < 8; ++i) v[i] = (__bf16)0.f;
        if (c < 25) {
            v = *reinterpret_cast<const bf16x8*>(&Ab[(size_t)r * 256 + c * 8]);
            if (c == 24) { v[4] = (__bf16)0.f; v[5] = (__bf16)0.f; v[6] = (__bf16)0.f; v[7] = (__bf16)0.f; }
        }
        *reinterpret_cast<bf16x8*>(&Alds[r * 256 + c * 8]) = v;
    }
    {
        ushort4 z = {0, 0, 0, 0};
        for (int idx = tid; idx < 28 * 64; idx += 512) {
            int r = 196 + (idx >> 6), c4 = (idx & 63) << 2;
            *reinterpret_cast<ushort4*>(&Alds[r * 256 + c4]) = z;
        }
    }
    __syncthreads();

    float P[7][16];
#pragma unroll
    for (int k = 0; k < 7; ++k)
#pragma unroll
        for (int e = 0; e < 16; ++e) P[k][e] = 1.f;

    float sr[16];
#pragma unroll
    for (int e = 0; e < 16; ++e) {
        int j = (e < 8) ? (colbase + e) : (colbase + 128 + (e - 8));
        sr[e] = (j < NSP) ? MIU : 0.f;
    }

    for (int it = 0; it < 20; ++it) {
        float cs[16];
#pragma unroll
        for (int e = 0; e < 16; ++e) cs[e] = 0.f;

#pragma unroll
        for (int k = 0; k < 7; ++k) {
            const __bf16* ap = &Alds[(g + 32 * k) * 256 + colbase];
            bf16x8 a0 = *reinterpret_cast<const bf16x8*>(ap);
            bf16x8 a1 = *reinterpret_cast<const bf16x8*>(ap + 128);
            float r0 = 0.f, r1 = 0.f;
#pragma unroll
            for (int e = 0; e < 8; ++e) {
                P[k][e] *= (float)a0[e];
                r0 = fmaf(P[k][e], sr[e], r0);
            }
#pragma unroll
            for (int e = 0; e < 8; ++e) {
                P[k][8 + e] *= (float)a1[e];
                r1 = fmaf(P[k][8 + e], sr[8 + e], r1);
            }
            float racc = row16_sum(r0 + r1);
            float delta = MIU * __builtin_amdgcn_rcpf(racc + 1e-6f);
#pragma unroll
            for (int e = 0; e < 16; ++e) {
                P[k][e] *= delta;
                cs[e] += P[k][e];
            }
        }
        {
            float* cp = &cpart[g * 260 + colbase];
            *reinterpret_cast<f32x4*>(cp)     = f32x4{cs[0], cs[1], cs[2], cs[3]};
            *reinterpret_cast<f32x4*>(cp + 4) = f32x4{cs[4], cs[5], cs[6], cs[7]};
            float* cp2 = cp + 128;
            *reinterpret_cast<f32x4*>(cp2)     = f32x4{cs[8], cs[9], cs[10], cs[11]};
            *reinterpret_cast<f32x4*>(cp2 + 4) = f32x4{cs[12], cs[13], cs[14], cs[15]};
        }
        __syncthreads();
        if (tid < 256) {
            float s0 = 0.f, s1 = 0.f, s2 = 0.f, s3 = 0.f;
#pragma unroll
            for (int gg = 0; gg < 32; gg += 4) {
                s0 += cpart[(gg + 0) * 260 + tid];
                s1 += cpart[(gg + 1) * 260 + tid];
                s2 += cpart[(gg + 2) * 260 + tid];
                s3 += cpart[(gg + 3) * 260 + tid];
            }
            float sum = (s0 + s1) + (s2 + s3);
            svec[it & 1][tid] = (tid < NSP) ? (MIU * __builtin_amdgcn_rcpf(sum + 1e-6f)) : 0.f;
        }
        __syncthreads();
        {
            const float* sv = svec[it & 1];
            f32x4 t0 = *reinterpret_cast<const f32x4*>(&sv[colbase]);
            f32x4 t1 = *reinterpret_cast<const f32x4*>(&sv[colbase + 4]);
            f32x4 t2 = *reinterpret_cast<const f32x4*>(&sv[colbase + 128]);
            f32x4 t3 = *reinterpret_cast<const f32x4*>(&sv[colbase + 132]);
            sr[0] = t0.x; sr[1] = t0.y; sr[2] = t0.z; sr[3] = t0.w;
            sr[4] = t1.x; sr[5] = t1.y; sr[6] = t1.z; sr[7] = t1.w;
            sr[8] = t2.x; sr[9] = t2.y; sr[10] = t2.z; sr[11] = t2.w;
            sr[12] = t3.x; sr[13] = t3.y; sr[14] = t3.z; sr[15] = t3.w;
        }
#pragma unroll
        for (int k = 0; k < 7; ++k)
#pragma unroll
            for (int e = 0; e < 16; ++e) P[k][e] *= sr[e];
    }

    float acc = 0.f;
#pragma unroll
    for (int k = 0; k < 7; ++k) {
        const __bf16* ap = &Alds[(g + 32 * k) * 256 + colbase];
        bf16x8 a0 = *reinterpret_cast<const bf16x8*>(ap);
        bf16x8 a1 = *reinterpret_cast<const bf16x8*>(ap + 128);
#pragma unroll
        for (int e = 0; e < 8; ++e) {
            acc = fmaf(P[k][e],     -0.5f * __logf(fmaxf((float)a0[e], 1e-30f)), acc);
            acc = fmaf(P[k][8 + e], -0.5f * __logf(fmaxf((float)a1[e], 1e-30f)), acc);
        }
    }
    acc = row16_sum(acc);
    acc += __shfl_xor(acc, 16);
    acc += __shfl_xor(acc, 32);
    if (lane == 0) wsum[w] = acc;
    __syncthreads();
    if (tid == 0) {
        float t = 0.f;
#pragma unroll
        for (int i = 0; i < 8; ++i) t += wsum[i];
        atomicAdd(out, -t * (1.f / BS));
    }
}

extern "C" void kernel_launch(void* const* d_in, const int* in_sizes, int n_in,
                              void* d_out, int out_size, void* d_ws, size_t ws_size,
                              hipStream_t stream)
{
    const float* sp1 = (const float*)d_in[0];
    const float* sp2 = (const float*)d_in[1];
    const float* tm1 = (const float*)d_in[2];
    const float* tm2 = (const float*)d_in[3];
    float* out = (float*)d_out;
    float* ws  = (float*)d_ws;

    float* inx_tm = ws;                          // 4096
    float* iny_tm = inx_tm + BS * NTM;           // 4096
    float* A_tm   = iny_tm + BS * NTM;           // 131072 f32
    __bf16* A_sp  = (__bf16*)(ws + 139264);      // 128*256*256 bf16 = 33,554,432 B

    tm_norm_kernel<<<dim3(2048), 256, 0, stream>>>(tm1, tm2, inx_tm, iny_tm);

    cost_gemm_v2<<<dim3(1024), 256, 0, stream>>>(sp1, sp2, A_sp);

    cost_gemm<16, 2, 32, NTM><<<dim3(1, BS), 128, 0, stream>>>(tm1, tm2, inx_tm, iny_tm, A_tm);

    (void)hipMemsetAsync(d_out, 0, sizeof(float), stream);

    ipot_dpp<<<dim3(256), 512, 0, stream>>>(A_sp, A_tm, out);
}

// Round 13
// 158.122 us; speedup vs baseline: 1.8869x; 1.8869x over previous
//
#include <hip/hip_runtime.h>
#include <hip/hip_bf16.h>
#include <cstdint>

typedef float f32x4 __attribute__((ext_vector_type(4)));
typedef __bf16 bf16x8 __attribute__((ext_vector_type(8)));

#define BS 128
#define NSP 196
#define NTM 32
#define DDIM 768

__device__ inline ushort4 f4_to_bf4(float4 v)
{
    ushort4 u;
    u.x = __builtin_bit_cast(unsigned short, (__bf16)v.x);
    u.y = __builtin_bit_cast(unsigned short, (__bf16)v.y);
    u.z = __builtin_bit_cast(unsigned short, (__bf16)v.z);
    u.w = __builtin_bit_cast(unsigned short, (__bf16)v.w);
    return u;
}

__device__ inline bf16x8 f4x2_to_bf8(float4 lo, float4 hi)
{
    bf16x8 r;
    r[0] = (__bf16)lo.x; r[1] = (__bf16)lo.y; r[2] = (__bf16)lo.z; r[3] = (__bf16)lo.w;
    r[4] = (__bf16)hi.x; r[5] = (__bf16)hi.y; r[6] = (__bf16)hi.z; r[7] = (__bf16)hi.w;
    return r;
}

__device__ inline float sumsq4(float4 a)
{
    return fmaf(a.x, a.x, fmaf(a.y, a.y, fmaf(a.z, a.z, a.w * a.w)));
}

// sum over the 16-lane DPP row; every lane gets the total.
__device__ inline float row16_sum(float x)
{
    int t;
    t = __builtin_amdgcn_update_dpp(0, __builtin_bit_cast(int, x), 0x121, 0xf, 0xf, true);
    x += __builtin_bit_cast(float, t);
    t = __builtin_amdgcn_update_dpp(0, __builtin_bit_cast(int, x), 0x122, 0xf, 0xf, true);
    x += __builtin_bit_cast(float, t);
    t = __builtin_amdgcn_update_dpp(0, __builtin_bit_cast(int, x), 0x124, 0xf, 0xf, true);
    x += __builtin_bit_cast(float, t);
    t = __builtin_amdgcn_update_dpp(0, __builtin_bit_cast(int, x), 0x128, 0xf, 0xf, true);
    x += __builtin_bit_cast(float, t);
    return x;
}

// ---------------- temporal row inverse-norms only ----------------
__global__ __launch_bounds__(256)
void tm_norm_kernel(const float* __restrict__ tm1, const float* __restrict__ tm2,
                    float* __restrict__ inx_tm, float* __restrict__ iny_tm)
{
    int B = blockIdx.x;
    const float* src; float* inv;
    if (B < 1024) { src = tm1; inv = inx_tm; }
    else          { B -= 1024; src = tm2; inv = iny_tm; }
    const int row  = B * 4 + (threadIdx.x >> 6);
    const int lane = threadIdx.x & 63;
    const float4* p = reinterpret_cast<const float4*>(src + (size_t)row * DDIM);
    float ss = 0.f;
#pragma unroll
    for (int c = 0; c < 3; ++c) ss += sumsq4(p[lane + 64 * c]);
#pragma unroll
    for (int off = 32; off; off >>= 1) ss += __shfl_xor(ss, off, 64);
    if (lane == 0) inv[row] = 1.0f / (sqrtf(ss) + 1e-12f);
}

// ============== spatial cost GEMM, f32 inputs + fused row norms ==============
// Grid 512 = 8 XCD * 16 batch * 4 coltile. Block 448 thr (7 waves).
// Tile 224x64, BK=64, dbuf LDS + XOR slot swizzle.
// KEY (R13): LOADS(kt+1) issued AFTER the first barrier, so the compiler's
// pre-barrier vmcnt(0) drain lands at the SECOND barrier with the whole
// ds_read+MFMA phase as latency cover (was: drained immediately, ~900cyc
// exposed per K-tile — the measured 16K cyc/iter).
#define GA_LDS 18432
__global__ __launch_bounds__(448)
void cost_gemm_spf(const float* __restrict__ X, const float* __restrict__ Y,
                   __bf16* __restrict__ Aout)
{
    __shared__ __bf16 lds[2 * GA_LDS];
    float* ldsF = reinterpret_cast<float*>(lds);

    const int flat  = blockIdx.x;
    const int xcd   = flat & 7;
    const int s     = flat >> 3;
    const int b     = xcd * 16 + (s >> 2);
    const int ctile = s & 3;
    const int n0    = (ctile < 3) ? ctile * 64 : 132;

    const int tid  = threadIdx.x;
    const int w    = tid >> 6, lane = tid & 63;
    const int q    = lane >> 4, l16 = lane & 15;
    const int srow = tid >> 3;          // 0..55
    const int sslt = tid & 7;           // 0..7

    const float* Yb = Y + (size_t)b * NSP * DDIM;

    float4 aL[4], aH[4], bL, bH, b2L, b2H;
    float ssA[4] = {0.f, 0.f, 0.f, 0.f};
    float ssB = 0.f, ssB2 = 0.f;

    auto LOADS = [&](int k0) {
#pragma unroll
        for (int p = 0; p < 4; ++p) {
            int gr = b * NSP + srow + 56 * p;
            gr = min(gr, BS * NSP - 1);
            const float* sp = X + (size_t)gr * DDIM + k0 + sslt * 8;
            aL[p] = *reinterpret_cast<const float4*>(sp);
            aH[p] = *reinterpret_cast<const float4*>(sp + 4);
        }
        {
            const float* sp = Yb + (size_t)(n0 + srow) * DDIM + k0 + sslt * 8;
            bL = *reinterpret_cast<const float4*>(sp);
            bH = *reinterpret_cast<const float4*>(sp + 4);
        }
        if (tid < 64) {
            const float* sp = Yb + (size_t)(n0 + 56 + srow) * DDIM + k0 + sslt * 8;
            b2L = *reinterpret_cast<const float4*>(sp);
            b2H = *reinterpret_cast<const float4*>(sp + 4);
        }
    };
    auto WRITES = [&](int buf) {
#pragma unroll
        for (int p = 0; p < 4; ++p) {
            int r = srow + 56 * p;
            ssA[p] += sumsq4(aL[p]) + sumsq4(aH[p]);
            *reinterpret_cast<bf16x8*>(&lds[buf * GA_LDS + r * 64 + ((sslt ^ (r & 7)) << 3)]) =
                f4x2_to_bf8(aL[p], aH[p]);
        }
        {
            int r = srow;
            ssB += sumsq4(bL) + sumsq4(bH);
            *reinterpret_cast<bf16x8*>(&lds[buf * GA_LDS + 14336 + r * 64 + ((sslt ^ (r & 7)) << 3)]) =
                f4x2_to_bf8(bL, bH);
        }
        if (tid < 64) {
            int r = 56 + srow;
            ssB2 += sumsq4(b2L) + sumsq4(b2H);
            *reinterpret_cast<bf16x8*>(&lds[buf * GA_LDS + 14336 + r * 64 + ((sslt ^ (r & 7)) << 3)]) =
                f4x2_to_bf8(b2L, b2H);
        }
    };

    f32x4 acc[2][4];
#pragma unroll
    for (int i = 0; i < 2; ++i)
#pragma unroll
        for (int j = 0; j < 4; ++j) acc[i][j] = f32x4{0.f, 0.f, 0.f, 0.f};

    LOADS(0);
    int buf = 0;
    for (int kt = 0; kt < 12; ++kt) {
        WRITES(buf);
        __syncthreads();
        if (kt < 11) LOADS((kt + 1) * 64);   // issued after barrier: drains at the
                                             // NEXT barrier, covered by MFMA phase
#pragma unroll
        for (int ks = 0; ks < 2; ++ks) {
            bf16x8 af[2], bf[4];
#pragma unroll
            for (int rt = 0; rt < 2; ++rt) {
                int r = w * 32 + rt * 16 + l16;
                af[rt] = *reinterpret_cast<const bf16x8*>(
                    &lds[buf * GA_LDS + r * 64 + (((ks * 4 + q) ^ (r & 7)) << 3)]);
            }
#pragma unroll
            for (int ct = 0; ct < 4; ++ct) {
                int r = ct * 16 + l16;
                bf[ct] = *reinterpret_cast<const bf16x8*>(
                    &lds[buf * GA_LDS + 14336 + r * 64 + (((ks * 4 + q) ^ (r & 7)) << 3)]);
            }
#pragma unroll
            for (int ct = 0; ct < 4; ++ct)
#pragma unroll
                for (int rt = 0; rt < 2; ++rt)
                    acc[rt][ct] = __builtin_amdgcn_mfma_f32_16x16x32_bf16(af[rt], bf[ct], acc[rt][ct], 0, 0, 0);
        }
        __syncthreads();
        buf ^= 1;
    }

    // ---- reduce norm partials through the (now free) LDS buffer ----
#pragma unroll
    for (int p = 0; p < 4; ++p) ldsF[(srow + 56 * p) * 8 + sslt] = ssA[p];
    ldsF[1792 + srow * 8 + sslt] = ssB;
    if (tid < 64) ldsF[1792 + (56 + srow) * 8 + sslt] = ssB2;
    __syncthreads();

    float ivy[4];
#pragma unroll
    for (int ct = 0; ct < 4; ++ct) {
        int jr = ct * 16 + l16;
        f32x4 s0 = *reinterpret_cast<const f32x4*>(&ldsF[1792 + jr * 8]);
        f32x4 s1 = *reinterpret_cast<const f32x4*>(&ldsF[1792 + jr * 8 + 4]);
        float ss = (s0.x + s0.y) + (s0.z + s0.w) + (s1.x + s1.y) + (s1.z + s1.w);
        ivy[ct] = 1.0f / (sqrtf(ss) + 1e-12f);
    }
#pragma unroll
    for (int rt = 0; rt < 2; ++rt)
#pragma unroll
        for (int rr = 0; rr < 4; ++rr) {
            int i = w * 32 + rt * 16 + q * 4 + rr;
            if (i < NSP) {
                f32x4 s0 = *reinterpret_cast<const f32x4*>(&ldsF[i * 8]);
                f32x4 s1 = *reinterpret_cast<const f32x4*>(&ldsF[i * 8 + 4]);
                float ss = (s0.x + s0.y) + (s0.z + s0.w) + (s1.x + s1.y) + (s1.z + s1.w);
                float ivx = 1.0f / (sqrtf(ss) + 1e-12f);
#pragma unroll
                for (int ct = 0; ct < 4; ++ct) {
                    float cs = acc[rt][ct][rr] * ivx * ivy[ct];
                    Aout[(size_t)b * 65536 + (size_t)i * 256 + (n0 + ct * 16 + l16)] =
                        (__bf16)__expf(2.0f * cs - 2.0f);
                }
            }
        }
}

// ---------------- temporal cost GEMM (f32 in/out) ----------------
template<int WROWS, int NWAVES, int BN, int NPTS>
__global__ __launch_bounds__(NWAVES * 64)
void cost_gemm(const float* __restrict__ X, const float* __restrict__ Y,
               const float* __restrict__ invx, const float* __restrict__ invy,
               float* __restrict__ Aout)
{
    constexpr int MT = WROWS * NWAVES;
    constexpr int CT = BN / 16;
    constexpr int RT = WROWS / 16;
    constexpr int KP = 40;
    constexpr int NTH = NWAVES * 64;
    __shared__ __bf16 As[MT][KP];
    __shared__ __bf16 Bs[BN][KP];

    const int b    = blockIdx.y;
    const int row0 = blockIdx.x * MT;
    const int tid  = threadIdx.x;
    const int w    = tid >> 6, lane = tid & 63;
    const int q    = lane >> 4, l16 = lane & 15;
    const float* Xb = X + (size_t)b * NPTS * DDIM;
    const float* Yb = Y + (size_t)b * NPTS * DDIM;

    f32x4 acc[RT][CT];
#pragma unroll
    for (int i = 0; i < RT; ++i)
#pragma unroll
        for (int j = 0; j < CT; ++j) acc[i][j] = f32x4{0.f, 0.f, 0.f, 0.f};

    for (int k0 = 0; k0 < DDIM; k0 += 32) {
        __syncthreads();
        for (int idx = tid * 4; idx < MT * 32; idx += NTH * 4) {
            int r = idx >> 5, kk = idx & 31;
            int gr = row0 + r;
            float4 v = {0.f, 0.f, 0.f, 0.f};
            if (gr < NPTS) v = *reinterpret_cast<const float4*>(Xb + (size_t)gr * DDIM + k0 + kk);
            *reinterpret_cast<ushort4*>(&As[r][kk]) = f4_to_bf4(v);
        }
        for (int idx = tid * 4; idx < BN * 32; idx += NTH * 4) {
            int r = idx >> 5, kk = idx & 31;
            float4 v = {0.f, 0.f, 0.f, 0.f};
            if (r < NPTS) v = *reinterpret_cast<const float4*>(Yb + (size_t)r * DDIM + k0 + kk);
            *reinterpret_cast<ushort4*>(&Bs[r][kk]) = f4_to_bf4(v);
        }
        __syncthreads();

        bf16x8 af[RT];
#pragma unroll
        for (int rt = 0; rt < RT; ++rt)
            af[rt] = *reinterpret_cast<const bf16x8*>(&As[w * WROWS + rt * 16 + l16][q * 8]);
#pragma unroll
        for (int ct = 0; ct < CT; ++ct) {
            bf16x8 bfr = *reinterpret_cast<const bf16x8*>(&Bs[ct * 16 + l16][q * 8]);
#pragma unroll
            for (int rt = 0; rt < RT; ++rt)
                acc[rt][ct] = __builtin_amdgcn_mfma_f32_16x16x32_bf16(af[rt], bfr, acc[rt][ct], 0, 0, 0);
        }
    }

#pragma unroll
    for (int rt = 0; rt < RT; ++rt)
#pragma unroll
        for (int ct = 0; ct < CT; ++ct)
#pragma unroll
            for (int rr = 0; rr < 4; ++rr) {
                int i = row0 + w * WROWS + rt * 16 + q * 4 + rr;
                int j = ct * 16 + l16;
                if (i < NPTS && j < NPTS) {
                    float g  = acc[rt][ct][rr];
                    float cs = g * invx[b * NPTS + i] * invy[b * NPTS + j];
                    Aout[(size_t)b * NPTS * NPTS + (size_t)i * NPTS + j] = expf(-2.0f * (1.0f - cs));
                }
            }
}

// ========== fused IPOT v6: DPP rowsum, 512 thr, A in LDS ==========
__global__ __launch_bounds__(512, 1)
void ipot_dpp(const __bf16* __restrict__ Asp, const float* __restrict__ Atm,
              float* __restrict__ out)
{
    __shared__ __bf16 Alds[224 * 256];    // 114,688 B
    __shared__ float  cpart[32 * 260];    //  33,280 B
    __shared__ float  svec[2][272];
    __shared__ float  wsum[8];

    const int B = blockIdx.x;
    if (B >= 128) {
        if (threadIdx.x >= 64) return;
        const int b = B - 128;
        const float* Ab = Atm + (size_t)b * NTM * NTM;
        const int lane = threadIdx.x;
        const int rh = lane >> 5, cj = lane & 31;
        constexpr float MIU = 1.f / NTM;
        float A[16], P[16];
#pragma unroll
        for (int k = 0; k < 16; ++k) {
            A[k] = Ab[(rh + 2 * k) * NTM + cj];
            P[k] = 1.f;
        }
        float sv = MIU;
        for (int it = 0; it < 20; ++it) {
#pragma unroll
            for (int k = 0; k < 16; ++k) {
                P[k] *= A[k];
                float acc = row16_sum(P[k] * sv);
                acc += __shfl_xor(acc, 16);
                P[k] *= MIU * __builtin_amdgcn_rcpf(acc + 1e-6f);
            }
            float cssum = 0.f;
#pragma unroll
            for (int k = 0; k < 16; ++k) cssum += P[k];
            cssum += __shfl_xor(cssum, 32);
            float sg = MIU * __builtin_amdgcn_rcpf(cssum + 1e-6f);
#pragma unroll
            for (int k = 0; k < 16; ++k) P[k] *= sg;
            sv = sg;
        }
        float acc = 0.f;
#pragma unroll
        for (int k = 0; k < 16; ++k)
            acc = fmaf(P[k], -0.5f * __logf(A[k]), acc);
        acc = row16_sum(acc);
        acc += __shfl_xor(acc, 16);
        acc += __shfl_xor(acc, 32);
        if (lane == 0) atomicAdd(out, -acc * (1.f / BS));
        return;
    }

    const int b = (B & 7) * 16 + (B >> 3);
    const __bf16* Ab = Asp + (size_t)b * 65536;
    const int tid = threadIdx.x;
    const int w = tid >> 6, lane = tid & 63;
    const int rq = lane >> 4, cl = lane & 15;
    const int g = w * 4 + rq;
    const int colbase = cl * 8;
    constexpr float MIU = 1.f / NSP;

    for (int idx = tid; idx < NSP * 32; idx += 512) {
        int r = idx >> 5, c = idx & 31;
        bf16x8 v;
#pragma unroll
        for (int i = 0; i < 8; ++i) v[i] = (__bf16)0.f;
        if (c < 25) {
            v = *reinterpret_cast<const bf16x8*>(&Ab[(size_t)r * 256 + c * 8]);
            if (c == 24) { v[4] = (__bf16)0.f; v[5] = (__bf16)0.f; v[6] = (__bf16)0.f; v[7] = (__bf16)0.f; }
        }
        *reinterpret_cast<bf16x8*>(&Alds[r * 256 + c * 8]) = v;
    }
    {
        ushort4 z = {0, 0, 0, 0};
        for (int idx = tid; idx < 28 * 64; idx += 512) {
            int r = 196 + (idx >> 6), c4 = (idx & 63) << 2;
            *reinterpret_cast<ushort4*>(&Alds[r * 256 + c4]) = z;
        }
    }
    __syncthreads();

    float P[7][16];
#pragma unroll
    for (int k = 0; k < 7; ++k)
#pragma unroll
        for (int e = 0; e < 16; ++e) P[k][e] = 1.f;

    float sr[16];
#pragma unroll
    for (int e = 0; e < 16; ++e) {
        int j = (e < 8) ? (colbase + e) : (colbase + 128 + (e - 8));
        sr[e] = (j < NSP) ? MIU : 0.f;
    }

    for (int it = 0; it < 20; ++it) {
        float cs[16];
#pragma unroll
        for (int e = 0; e < 16; ++e) cs[e] = 0.f;

#pragma unroll
        for (int k = 0; k < 7; ++k) {
            const __bf16* ap = &Alds[(g + 32 * k) * 256 + colbase];
            bf16x8 a0 = *reinterpret_cast<const bf16x8*>(ap);
            bf16x8 a1 = *reinterpret_cast<const bf16x8*>(ap + 128);
            float r0 = 0.f, r1 = 0.f;
#pragma unroll
            for (int e = 0; e < 8; ++e) {
                P[k][e] *= (float)a0[e];
                r0 = fmaf(P[k][e], sr[e], r0);
            }
#pragma unroll
            for (int e = 0; e < 8; ++e) {
                P[k][8 + e] *= (float)a1[e];
                r1 = fmaf(P[k][8 + e], sr[8 + e], r1);
            }
            float racc = row16_sum(r0 + r1);
            float delta = MIU * __builtin_amdgcn_rcpf(racc + 1e-6f);
#pragma unroll
            for (int e = 0; e < 16; ++e) {
                P[k][e] *= delta;
                cs[e] += P[k][e];
            }
        }
        {
            float* cp = &cpart[g * 260 + colbase];
            *reinterpret_cast<f32x4*>(cp)     = f32x4{cs[0], cs[1], cs[2], cs[3]};
            *reinterpret_cast<f32x4*>(cp + 4) = f32x4{cs[4], cs[5], cs[6], cs[7]};
            float* cp2 = cp + 128;
            *reinterpret_cast<f32x4*>(cp2)     = f32x4{cs[8], cs[9], cs[10], cs[11]};
            *reinterpret_cast<f32x4*>(cp2 + 4) = f32x4{cs[12], cs[13], cs[14], cs[15]};
        }
        __syncthreads();
        if (tid < 256) {
            float s0 = 0.f, s1 = 0.f, s2 = 0.f, s3 = 0.f;
#pragma unroll
            for (int gg = 0; gg < 32; gg += 4) {
                s0 += cpart[(gg + 0) * 260 + tid];
                s1 += cpart[(gg + 1) * 260 + tid];
                s2 += cpart[(gg + 2) * 260 + tid];
                s3 += cpart[(gg + 3) * 260 + tid];
            }
            float sum = (s0 + s1) + (s2 + s3);
            svec[it & 1][tid] = (tid < NSP) ? (MIU * __builtin_amdgcn_rcpf(sum + 1e-6f)) : 0.f;
        }
        __syncthreads();
        {
            const float* sv = svec[it & 1];
            f32x4 t0 = *reinterpret_cast<const f32x4*>(&sv[colbase]);
            f32x4 t1 = *reinterpret_cast<const f32x4*>(&sv[colbase + 4]);
            f32x4 t2 = *reinterpret_cast<const f32x4*>(&sv[colbase + 128]);
            f32x4 t3 = *reinterpret_cast<const f32x4*>(&sv[colbase + 132]);
            sr[0] = t0.x; sr[1] = t0.y; sr[2] = t0.z; sr[3] = t0.w;
            sr[4] = t1.x; sr[5] = t1.y; sr[6] = t1.z; sr[7] = t1.w;
            sr[8] = t2.x; sr[9] = t2.y; sr[10] = t2.z; sr[11] = t2.w;
            sr[12] = t3.x; sr[13] = t3.y; sr[14] = t3.z; sr[15] = t3.w;
        }
#pragma unroll
        for (int k = 0; k < 7; ++k)
#pragma unroll
            for (int e = 0; e < 16; ++e) P[k][e] *= sr[e];
    }

    float acc = 0.f;
#pragma unroll
    for (int k = 0; k < 7; ++k) {
        const __bf16* ap = &Alds[(g + 32 * k) * 256 + colbase];
        bf16x8 a0 = *reinterpret_cast<const bf16x8*>(ap);
        bf16x8 a1 = *reinterpret_cast<const bf16x8*>(ap + 128);
#pragma unroll
        for (int e = 0; e < 8; ++e) {
            acc = fmaf(P[k][e],     -0.5f * __logf(fmaxf((float)a0[e], 1e-30f)), acc);
            acc = fmaf(P[k][8 + e], -0.5f * __logf(fmaxf((float)a1[e], 1e-30f)), acc);
        }
    }
    acc = row16_sum(acc);
    acc += __shfl_xor(acc, 16);
    acc += __shfl_xor(acc, 32);
    if (lane == 0) wsum[w] = acc;
    __syncthreads();
    if (tid == 0) {
        float t = 0.f;
#pragma unroll
        for (int i = 0; i < 8; ++i) t += wsum[i];
        atomicAdd(out, -t * (1.f / BS));
    }
}

extern "C" void kernel_launch(void* const* d_in, const int* in_sizes, int n_in,
                              void* d_out, int out_size, void* d_ws, size_t ws_size,
                              hipStream_t stream)
{
    const float* sp1 = (const float*)d_in[0];
    const float* sp2 = (const float*)d_in[1];
    const float* tm1 = (const float*)d_in[2];
    const float* tm2 = (const float*)d_in[3];
    float* out = (float*)d_out;
    float* ws  = (float*)d_ws;

    float* inx_tm = ws;                          // 4096
    float* iny_tm = inx_tm + BS * NTM;           // 4096
    float* A_tm   = iny_tm + BS * NTM;           // 131072 f32
    __bf16* A_sp  = (__bf16*)(ws + 139264);      // 128*256*256 bf16 = 33,554,432 B

    tm_norm_kernel<<<dim3(2048), 256, 0, stream>>>(tm1, tm2, inx_tm, iny_tm);

    cost_gemm_spf<<<dim3(512), 448, 0, stream>>>(sp1, sp2, A_sp);

    cost_gemm<16, 2, 32, NTM><<<dim3(1, BS), 128, 0, stream>>>(tm1, tm2, inx_tm, iny_tm, A_tm);

    (void)hipMemsetAsync(d_out, 0, sizeof(float), stream);

    ipot_dpp<<<dim3(256), 512, 0, stream>>>(A_sp, A_tm, out);
}